// Round 19
// baseline (58.229 us; speedup 1.0000x reference)
//
#include <hip/hip_runtime.h>
#include <hip/hip_bf16.h>

typedef __bf16 bf16x8 __attribute__((ext_vector_type(8)));
typedef __bf16 bf16x4 __attribute__((ext_vector_type(4)));
typedef float  f32x4  __attribute__((ext_vector_type(4)));

#define LDP  72  // proj A-tile LDS row stride (padded; 2-way free)
#define KLDP 72  // attn K row stride (64 h + pad)
#define VLDP 72  // attn V row stride
#define PLDP 72  // attn P row stride

// Raw barrier: drain DS only; in-flight global loads survive (no vmcnt drain).
#define BAR() { asm volatile("s_waitcnt lgkmcnt(0)" ::: "memory"); __builtin_amdgcn_s_barrier(); }

// ---------------- Kernel 0: W -> bf16 + maskpack (fused) ----------------
__global__ __launch_bounds__(256) void wconv_kernel(
    const float* __restrict__ Wk, const float* __restrict__ Wq,
    const float* __restrict__ Wv, const int* __restrict__ mask,
    __bf16* __restrict__ wbf, unsigned* __restrict__ maskw)
{
    if (blockIdx.x == 192) {
        for (int wdx = threadIdx.x; wdx < 512; wdx += 256) {
            unsigned wv = 0;
            #pragma unroll
            for (int bit = 0; bit < 32; bit++)
                wv |= (mask[wdx * 32 + bit] != 0 ? 1u : 0u) << bit;
            maskw[wdx] = wv;
        }
        return;
    }
    int idx = blockIdx.x * 256 + threadIdx.x;
    int row = idx >> 8;
    int c4  = idx & 255;
    const float* wp = (row < 64) ? Wk + (size_t)row * 1024
                    : (row < 128) ? Wq + (size_t)(row - 64) * 1024
                                  : Wv + (size_t)(row - 128) * 1024;
    float4 f = *reinterpret_cast<const float4*>(wp + c4 * 4);
    bf16x4 v; v[0] = (__bf16)f.x; v[1] = (__bf16)f.y; v[2] = (__bf16)f.z; v[3] = (__bf16)f.w;
    *reinterpret_cast<bf16x4*>(&wbf[(size_t)row * 1024 + c4 * 4]) = v;
}

// ---------------- Kernel 1: proj GEMM, W staged via global_load_lds ----------------
// r15 structure (512 thr, 8 waves, 32x48 wave tiles, depth-2 A prefetch) with the
// W path converted to async global->LDS DMA: W is already bf16 in wbf, so its
// staging is a pure byte copy -- 3 global_load_lds(16B) per thread replaces
// 3 reg-loads + 3 ds_write_b128 (no VGPR round-trip; W leaves the A-commit chain).
// W LDS is unpadded [192][64] (linear dest required, m104); bank conflicts fixed
// by fetching global chunk (tid&7)^(row&7) and XORing the same on reads (m173).
// Counted vmcnt(2) before each barrier keeps the 2 A-prefetch loads in flight.
__global__ __launch_bounds__(512) void proj_kernel(
    const float* __restrict__ x, const __bf16* __restrict__ wbf,
    __bf16* __restrict__ kbuf, __bf16* __restrict__ qbuf, __bf16* __restrict__ vtbuf)
{
    __shared__ __align__(16) __bf16 Alds[2][64 * LDP];    // 2 x 9.2 KB, padded
    __shared__ __align__(16) __bf16 Wlds[2][192 * 64];    // 2 x 24 KB, linear+swizzled
    __shared__ __align__(16) __bf16 Vtl[64 * LDP];

    const int tid  = threadIdx.x;
    const int lane = tid & 63;
    const int wid  = tid >> 6;     // 0..7
    const int wm   = wid >> 2;     // 0..1 : 32-row group
    const int wn   = wid & 3;      // 0..3 : 48-col group
    const int mbase = blockIdx.x * 64;

    const int cl  = lane & 15;
    const int hi4 = lane >> 4;         // 0..3
    const int e0  = hi4 * 8;
    const int r0  = hi4 * 4;

    // A staging: thread -> row tid>>3 (0..63), 8 fp32 at col (tid&7)*8
    const int arow = tid >> 3, acg = tid & 7;
    const float* aptr = x + (size_t)(mbase + arow) * 1024 + acg * 8;

    // W gload: thread's row and swizzled source chunk (constant across iters)
    const int wrow = (tid >> 3) + 0;   // i_=0 row base; i_ adds 64 rows
    float4 a0a, a0b, a1a, a1b;

#define ISSUE_A(aA, aB, kb) { \
    aA = *reinterpret_cast<const float4*>(aptr + (kb)); \
    aB = *reinterpret_cast<const float4*>(aptr + (kb) + 4); }

#define COMMIT_A(aA, aB, bufi) { \
    bf16x8 av_; \
    av_[0] = (__bf16)aA.x; av_[1] = (__bf16)aA.y; av_[2] = (__bf16)aA.z; av_[3] = (__bf16)aA.w; \
    av_[4] = (__bf16)aB.x; av_[5] = (__bf16)aB.y; av_[6] = (__bf16)aB.z; av_[7] = (__bf16)aB.w; \
    *reinterpret_cast<bf16x8*>(&Alds[bufi][arow * LDP + acg * 8]) = av_; }

// async W copy: 3 x 1KB/wave; LDS dest linear (uniform base + lane*16);
// global src chunk permuted by (tid&7)^(row&7) so swizzled reads are conflict-free
#define W_GLOAD(kb, bufi) { \
    _Pragma("unroll") \
    for (int i_ = 0; i_ < 3; i_++) { \
        int row_ = ((i_ * 512 + tid) >> 3); \
        const __bf16* g_ = &wbf[(size_t)row_ * 1024 + (kb) + (((tid & 7) ^ (row_ & 7)) << 3)]; \
        __bf16* l_ = &Wlds[bufi][(size_t)(i_ * 512 + (tid & ~63)) * 8]; \
        __builtin_amdgcn_global_load_lds( \
            (const __attribute__((address_space(1))) void*)g_, \
            (__attribute__((address_space(3))) void*)l_, 16, 0, 0); \
    } }

    f32x4 acc[2][3];
    #pragma unroll
    for (int m2 = 0; m2 < 2; m2++)
        #pragma unroll
        for (int nf = 0; nf < 3; nf++) acc[m2][nf] = (f32x4){0.f, 0.f, 0.f, 0.f};

    // prologue
    ISSUE_A(a0a, a0b, 0);
    COMMIT_A(a0a, a0b, 0);
    W_GLOAD(0, 0);
    ISSUE_A(a1a, a1b, 64);
    asm volatile("s_waitcnt vmcnt(2) lgkmcnt(0)" ::: "memory");   // W(0) landed; A(1) in flight
    __builtin_amdgcn_s_barrier();

    #pragma unroll 2
    for (int j = 0; j < 16; j++) {
        // issue next W into the buffer sealed by the previous barrier
        if (j < 15) W_GLOAD((j + 1) * 64, (j & 1) ^ 1);
        if (j < 14) {
            if (j & 1) { ISSUE_A(a1a, a1b, (j + 2) * 64); }
            else       { ISSUE_A(a0a, a0b, (j + 2) * 64); }
        }
        const __bf16* abuf = Alds[j & 1];
        const __bf16* wbuf = Wlds[j & 1];
        #pragma unroll
        for (int kk = 0; kk < 2; kk++) {
            bf16x8 a[2], b[3];
            #pragma unroll
            for (int m2 = 0; m2 < 2; m2++)
                a[m2] = *reinterpret_cast<const bf16x8*>(&abuf[(wm * 32 + m2 * 16 + cl) * LDP + kk * 32 + e0]);
            #pragma unroll
            for (int nf = 0; nf < 3; nf++) {
                int r = wn * 48 + nf * 16 + cl;
                b[nf] = *reinterpret_cast<const bf16x8*>(&wbuf[r * 64 + (((kk * 4 + hi4) ^ (r & 7)) << 3)]);
            }
            #pragma unroll
            for (int m2 = 0; m2 < 2; m2++)
                #pragma unroll
                for (int nf = 0; nf < 3; nf++)
                    acc[m2][nf] = __builtin_amdgcn_mfma_f32_16x16x32_bf16(a[m2], b[nf], acc[m2][nf], 0, 0, 0);
        }
        if (j < 15) {
            if (j & 1) { COMMIT_A(a0a, a0b, 0); }
            else       { COMMIT_A(a1a, a1b, 1); }
            // my W(j+1) gloads must land before crossing (all waves do likewise);
            // A(j+2) prefetches stay in flight (counted, never drained mid-loop)
            if (j < 14) { asm volatile("s_waitcnt vmcnt(2) lgkmcnt(0)" ::: "memory"); }
            else        { asm volatile("s_waitcnt vmcnt(0) lgkmcnt(0)" ::: "memory"); }
            __builtin_amdgcn_s_barrier();
        }
    }
#undef ISSUE_A
#undef COMMIT_A
#undef W_GLOAD

    #pragma unroll
    for (int m2 = 0; m2 < 2; m2++)
        #pragma unroll
        for (int nf = 0; nf < 3; nf++) {
            int c = wn * 48 + nf * 16 + cl;
            #pragma unroll
            for (int r = 0; r < 4; r++) {
                int mrel = wm * 32 + m2 * 16 + r0 + r;
                float v = acc[m2][nf][r];
                if (c < 64)        kbuf[(size_t)(mbase + mrel) * 64 + c]         = (__bf16)v;
                else if (c < 128)  qbuf[(size_t)(mbase + mrel) * 64 + (c - 64)]  = (__bf16)v;
                else               Vtl[(c - 128) * LDP + mrel]                   = (__bf16)v;
            }
        }
    __syncthreads();
    {
        int b   = mbase >> 11;
        int tof = mbase & 2047;
        int h   = tid >> 3;          // 0..63
        int seg = tid & 7;           // 8 bf16 each
        bf16x8 v8 = *reinterpret_cast<const bf16x8*>(&Vtl[h * LDP + seg * 8]);
        *reinterpret_cast<bf16x8*>(&vtbuf[(size_t)b * 64 * 2048 + (size_t)h * 2048 + tof + seg * 8]) = v8;
    }
}

// ---------------- Kernel 2: flash attention, 4 waves x 2 subtiles, 128 q-rows/block (r18 exact) ----
__global__ __launch_bounds__(256) void attn_kernel(
    const __bf16* __restrict__ qbuf, const __bf16* __restrict__ kbuf,
    const __bf16* __restrict__ vtbuf, const unsigned* __restrict__ maskw,
    float* __restrict__ out, __bf16* __restrict__ accpart, float* __restrict__ mlpart,
    int nsplit, int tps)
{
    __shared__ __align__(16) __bf16 Klds[64 * KLDP];        // [kv][h]
    __shared__ __align__(16) __bf16 Vlds[64 * VLDP];        // [h][kv]
    __shared__ __align__(16) __bf16 Plds[4][2][16 * PLDP];  // [wave][sub][q][kv]

    const int tid  = threadIdx.x;
    const int lane = tid & 63;
    const int w    = tid >> 6;          // 0..3
    const int wg   = blockIdx.x;
    const int b    = wg & 7;            // XCD-local batch
    const int rr_  = wg >> 3;
    const int qt   = rr_ & 15;          // 16 q-tiles of 128 rows
    const int sp   = rr_ >> 4;

    const int jbeg = sp * tps;
    const int jend = min((sp + 1) * tps, 2 * qt + 2);   // 64-wide kv tiles

    if (nsplit > 1 && jbeg >= jend) {
        for (int i = tid; i < 128; i += 256) {
            int qrow = qt * 128 + i;
            if ((maskw[b * 64 + (qrow >> 5)] >> (qrow & 31)) & 1u) {
                size_t mo = ((size_t)(b * nsplit + sp) * 2048 + qrow) * 2;
                mlpart[mo] = -INFINITY; mlpart[mo + 1] = 0.f;
            }
        }
        return;
    }

    const int cl = lane & 15;
    const int e0 = (lane >> 4) * 8;
    const int r0 = (lane >> 4) * 4;
    const int qs0 = qt * 128 + w * 16 + cl;   // subtile 0 q-row (lane-local)
    const int qs1 = qs0 + 64;                 // subtile 1 q-row

    bf16x8 aq0[2], aq1[2];
    #pragma unroll
    for (int kk = 0; kk < 2; kk++) {
        aq0[kk] = *reinterpret_cast<const bf16x8*>(&qbuf[((size_t)b * 2048 + qs0) * 64 + kk * 32 + e0]);
        aq1[kk] = *reinterpret_cast<const bf16x8*>(&qbuf[((size_t)b * 2048 + qs1) * 64 + kk * 32 + e0]);
    }

    float m0 = -INFINITY, l0 = 0.f, m1 = -INFINITY, l1 = 0.f;
    f32x4 acc0[4], acc1[4];
    #pragma unroll
    for (int hf = 0; hf < 4; hf++) { acc0[hf] = (f32x4){0.f,0.f,0.f,0.f}; acc1[hf] = (f32x4){0.f,0.f,0.f,0.f}; }

    const __bf16* kb  = kbuf  + (size_t)b * 2048 * 64;
    const __bf16* vtb = vtbuf + (size_t)b * 64 * 2048;

    // staging: 256 threads, thread -> row tid>>2 (0..63), 16-elem quarter (tid&3)
    const int srow = tid >> 2;
    const int sc   = (tid & 3) * 16;
    bf16x8 stk[2], stv[2];

#define KV_ISSUE(jj) { _Pragma("unroll") for (int i_ = 0; i_ < 2; i_++) { \
    stk[i_] = *reinterpret_cast<const bf16x8*>(&kb[(size_t)((jj) * 64 + srow) * 64 + sc + i_ * 8]); \
    stv[i_] = *reinterpret_cast<const bf16x8*>(&vtb[(size_t)srow * 2048 + (jj) * 64 + sc + i_ * 8]); } }

#define KV_COMMIT() { _Pragma("unroll") for (int i_ = 0; i_ < 2; i_++) { \
    *reinterpret_cast<bf16x8*>(&Klds[srow * KLDP + sc + i_ * 8]) = stk[i_]; \
    *reinterpret_cast<bf16x8*>(&Vlds[srow * VLDP + sc + i_ * 8]) = stv[i_]; } }

#define SOFTMAX(S, mS, lS, accS, qsS, su) { \
    float tmax = -INFINITY; \
    _Pragma("unroll") for (int jf = 0; jf < 4; jf++) { \
        unsigned mw = (jf < 2) ? mw0 : mw1; \
        _Pragma("unroll") for (int r = 0; r < 4; r++) { \
            int kvl = jf * 16 + r0 + r; \
            bool ok = ((mw >> (kvl & 31)) & 1u) && (j * 64 + kvl <= qsS); \
            float sv = S[jf][r] * 0.125f; \
            sv = ok ? sv : -INFINITY; \
            S[jf][r] = sv; tmax = fmaxf(tmax, sv); } } \
    tmax = fmaxf(tmax, __shfl_xor(tmax, 16)); \
    tmax = fmaxf(tmax, __shfl_xor(tmax, 32)); \
    if (!__all(tmax <= mS + 8.f)) { \
        float mn = fmaxf(mS, tmax); \
        float alpha = __expf(mS - mn); \
        lS *= alpha; mS = mn; \
        _Pragma("unroll") for (int hf = 0; hf < 4; hf++) \
            _Pragma("unroll") for (int r = 0; r < 4; r++) accS[hf][r] *= alpha; \
    } \
    float rs = 0.f; \
    _Pragma("unroll") for (int jf = 0; jf < 4; jf++) \
        _Pragma("unroll") for (int r = 0; r < 4; r++) { \
            float p = (mS == -INFINITY) ? 0.f : __expf(S[jf][r] - mS); \
            S[jf][r] = p; rs += p; } \
    rs += __shfl_xor(rs, 16); \
    rs += __shfl_xor(rs, 32); \
    lS += rs; \
    _Pragma("unroll") for (int jf = 0; jf < 4; jf++) { \
        bf16x4 p4; \
        _Pragma("unroll") for (int r = 0; r < 4; r++) p4[r] = (__bf16)S[jf][r]; \
        *reinterpret_cast<bf16x4*>(&Plds[w][su][cl * PLDP + jf * 16 + r0]) = p4; } }

    const int nt = jend - jbeg;
    KV_ISSUE(jbeg);
    KV_COMMIT();
    if (nt > 1) KV_ISSUE(jbeg + 1);
    BAR();

    for (int t = 0; t < nt; t++) {
        const int j = jbeg + t;

        f32x4 s0[4], s1[4];
        __builtin_amdgcn_s_setprio(1);
        #pragma unroll
        for (int jf = 0; jf < 4; jf++) {
            f32x4 t0 = (f32x4){0.f,0.f,0.f,0.f}, t1 = (f32x4){0.f,0.f,0.f,0.f};
            #pragma unroll
            for (int kk = 0; kk < 2; kk++) {
                bf16x8 bk = *reinterpret_cast<const bf16x8*>(&Klds[(jf * 16 + cl) * KLDP + kk * 32 + e0]);
                t0 = __builtin_amdgcn_mfma_f32_16x16x32_bf16(bk, aq0[kk], t0, 0, 0, 0);
                t1 = __builtin_amdgcn_mfma_f32_16x16x32_bf16(bk, aq1[kk], t1, 0, 0, 0);
            }
            s0[jf] = t0; s1[jf] = t1;
        }
        __builtin_amdgcn_s_setprio(0);

        const unsigned mw0 = maskw[b * 64 + j * 2];
        const unsigned mw1 = maskw[b * 64 + j * 2 + 1];
        SOFTMAX(s0, m0, l0, acc0, qs0, 0);
        SOFTMAX(s1, m1, l1, acc1, qs1, 1);

        __builtin_amdgcn_s_setprio(1);
        #pragma unroll
        for (int kk = 0; kk < 2; kk++) {
            bf16x8 p0 = *reinterpret_cast<const bf16x8*>(&Plds[w][0][cl * PLDP + kk * 32 + e0]);
            bf16x8 p1 = *reinterpret_cast<const bf16x8*>(&Plds[w][1][cl * PLDP + kk * 32 + e0]);
            #pragma unroll
            for (int hf = 0; hf < 4; hf++) {
                bf16x8 av = *reinterpret_cast<const bf16x8*>(&Vlds[(hf * 16 + cl) * VLDP + kk * 32 + e0]);
                acc0[hf] = __builtin_amdgcn_mfma_f32_16x16x32_bf16(av, p0, acc0[hf], 0, 0, 0);
                acc1[hf] = __builtin_amdgcn_mfma_f32_16x16x32_bf16(av, p1, acc1[hf], 0, 0, 0);
            }
        }
        __builtin_amdgcn_s_setprio(0);

        BAR();
        if (t + 1 < nt) {
            KV_COMMIT();
            if (t + 2 < nt) KV_ISSUE(j + 2);
            BAR();
        }
    }
#undef KV_ISSUE
#undef KV_COMMIT
#undef SOFTMAX

    const bool mq0 = (maskw[b * 64 + (qs0 >> 5)] >> (qs0 & 31)) & 1u;
    const bool mq1 = (maskw[b * 64 + (qs1 >> 5)] >> (qs1 & 31)) & 1u;
    if (nsplit == 1) {
        #pragma unroll
        for (int hf = 0; hf < 4; hf++)
            #pragma unroll
            for (int r = 0; r < 4; r++) {
                float v0 = (l0 > 0.f && mq0) ? acc0[hf][r] / l0 : 0.f;
                float v1 = (l1 > 0.f && mq1) ? acc1[hf][r] / l1 : 0.f;
                out[((size_t)b * 2048 + qs0) * 64 + hf * 16 + r0 + r] = v0;
                out[((size_t)b * 2048 + qs1) * 64 + hf * 16 + r0 + r] = v1;
            }
    } else {
        if (mq0) {
            #pragma unroll
            for (int hf = 0; hf < 4; hf++) {
                bf16x4 p4;
                #pragma unroll
                for (int r = 0; r < 4; r++) p4[r] = (__bf16)acc0[hf][r];
                *reinterpret_cast<bf16x4*>(&accpart[((size_t)(b * nsplit + sp) * 2048 + qs0) * 64 + hf * 16 + r0]) = p4;
            }
        }
        if (mq1) {
            #pragma unroll
            for (int hf = 0; hf < 4; hf++) {
                bf16x4 p4;
                #pragma unroll
                for (int r = 0; r < 4; r++) p4[r] = (__bf16)acc1[hf][r];
                *reinterpret_cast<bf16x4*>(&accpart[((size_t)(b * nsplit + sp) * 2048 + qs1) * 64 + hf * 16 + r0]) = p4;
            }
        }
        if (lane < 16) {
            if (mq0) {
                size_t mo0 = ((size_t)(b * nsplit + sp) * 2048 + qs0) * 2;
                mlpart[mo0] = m0; mlpart[mo0 + 1] = l0;
            }
            if (mq1) {
                size_t mo1 = ((size_t)(b * nsplit + sp) * 2048 + qs1) * 2;
                mlpart[mo1] = m1; mlpart[mo1 + 1] = l1;
            }
        }
    }
}

// ---------------- Kernel 3: combine bf16 partials, 4 h per thread ----------------
template<int NS>
__global__ __launch_bounds__(256) void combine_kernel(
    const __bf16* __restrict__ accpart, const float* __restrict__ mlpart,
    const unsigned* __restrict__ maskw, float* __restrict__ out)
{
    int idx = blockIdx.x * 256 + threadIdx.x;   // 0 .. 16384*16-1
    int qglob = idx >> 4;                        // b*2048 + qrow
    int h4 = (idx & 15) * 4;
    int b = qglob >> 11;
    int qrow = qglob & 2047;

    float4 o = {0.f, 0.f, 0.f, 0.f};
    if (!((maskw[b * 64 + (qrow >> 5)] >> (qrow & 31)) & 1u)) {
        *reinterpret_cast<float4*>(&out[(size_t)qglob * 64 + h4]) = o;
        return;
    }

    float m_s[NS], l_s[NS];
    float M = -INFINITY;
    #pragma unroll
    for (int s = 0; s < NS; s++) {
        size_t mo = ((size_t)(b * NS + s) * 2048 + qrow) * 2;
        m_s[s] = mlpart[mo];
        l_s[s] = mlpart[mo + 1];
        M = fmaxf(M, m_s[s]);
    }
    if (M == -INFINITY) {
        *reinterpret_cast<float4*>(&out[(size_t)qglob * 64 + h4]) = o;
        return;
    }

    float L = 0.f;
    float O0 = 0.f, O1 = 0.f, O2 = 0.f, O3 = 0.f;
    #pragma unroll
    for (int s = 0; s < NS; s++) {
        if (m_s[s] > -INFINITY) {
            float wgt = __expf(m_s[s] - M);
            L += l_s[s] * wgt;
            bf16x4 a = *reinterpret_cast<const bf16x4*>(
                &accpart[((size_t)(b * NS + s) * 2048 + qrow) * 64 + h4]);
            O0 += wgt * (float)a[0];
            O1 += wgt * (float)a[1];
            O2 += wgt * (float)a[2];
            O3 += wgt * (float)a[3];
        }
    }
    if (L > 0.f) { o.x = O0 / L; o.y = O1 / L; o.z = O2 / L; o.w = O3 / L; }
    *reinterpret_cast<float4*>(&out[(size_t)qglob * 64 + h4]) = o;
}

extern "C" void kernel_launch(void* const* d_in, const int* in_sizes, int n_in,
                              void* d_out, int out_size, void* d_ws, size_t ws_size,
                              hipStream_t stream) {
    const float* x  = (const float*)d_in[0];
    const float* Wk = (const float*)d_in[1];
    const float* Wq = (const float*)d_in[2];
    const float* Wv = (const float*)d_in[3];
    const int* mask = (const int*)d_in[4];
    float* out = (float*)d_out;

    const size_t NTOK = 8 * 2048;
    __bf16* kbuf  = (__bf16*)d_ws;                    // [16384][64]
    __bf16* qbuf  = kbuf + NTOK * 64;                 // [16384][64]
    __bf16* vtbuf = qbuf + NTOK * 64;                 // [8][64][2048]
    __bf16* wbf   = vtbuf + (size_t)8 * 64 * 2048;    // [192][1024]
    unsigned* maskw = (unsigned*)(wbf + (size_t)192 * 1024);   // [512]
    const size_t base_bytes = NTOK * 64 * 2 * 2 + (size_t)8 * 64 * 2048 * 2
                            + (size_t)192 * 1024 * 2 + 512 * 4;

    const size_t acc_per_split = NTOK * 64 * 2;       // bf16: 2 MiB
    const size_t ml_per_split  = NTOK * 2 * 4;        // 128 KiB
    int nsplit = 1;
    if (ws_size >= base_bytes + 4 * (acc_per_split + ml_per_split))      nsplit = 4;
    else if (ws_size >= base_bytes + 2 * (acc_per_split + ml_per_split)) nsplit = 2;

    __bf16* accpart = (__bf16*)((char*)d_ws + base_bytes);
    float*  mlpart  = (float*)(accpart + NTOK * 64 * nsplit);

    wconv_kernel<<<193, 256, 0, stream>>>(Wk, Wq, Wv, mask, wbf, maskw);
    proj_kernel<<<256, 512, 0, stream>>>(x, wbf, kbuf, qbuf, vtbuf);
    attn_kernel<<<8 * 16 * nsplit, 256, 0, stream>>>(
        qbuf, kbuf, vtbuf, maskw, out, accpart, mlpart, nsplit, 32 / nsplit);
    if (nsplit == 4)
        combine_kernel<4><<<(16384 * 16) / 256, 256, 0, stream>>>(accpart, mlpart, maskw, out);
    else if (nsplit == 2)
        combine_kernel<2><<<(16384 * 16) / 256, 256, 0, stream>>>(accpart, mlpart, maskw, out);
}

// Round 20
// 53.854 us; speedup vs baseline: 1.0812x; 1.0812x over previous
//
#include <hip/hip_runtime.h>
#include <hip/hip_bf16.h>

typedef __bf16 bf16x8 __attribute__((ext_vector_type(8)));
typedef __bf16 bf16x4 __attribute__((ext_vector_type(4)));
typedef float  f32x4  __attribute__((ext_vector_type(4)));

#define LDP  72  // proj LDS row stride
#define KLDP 72  // attn K row stride (64 h + pad)
#define VLDP 72  // attn V row stride
#define PLDP 72  // attn P row stride

// Raw barrier: drain DS only; in-flight global loads survive (no vmcnt drain).
#define BAR() { asm volatile("s_waitcnt lgkmcnt(0)" ::: "memory"); __builtin_amdgcn_s_barrier(); }

// ---------------- Kernel 0: W -> bf16 + maskpack (fused) ----------------
__global__ __launch_bounds__(256) void wconv_kernel(
    const float* __restrict__ Wk, const float* __restrict__ Wq,
    const float* __restrict__ Wv, const int* __restrict__ mask,
    __bf16* __restrict__ wbf, unsigned* __restrict__ maskw)
{
    if (blockIdx.x == 192) {
        for (int wdx = threadIdx.x; wdx < 512; wdx += 256) {
            unsigned wv = 0;
            #pragma unroll
            for (int bit = 0; bit < 32; bit++)
                wv |= (mask[wdx * 32 + bit] != 0 ? 1u : 0u) << bit;
            maskw[wdx] = wv;
        }
        return;
    }
    int idx = blockIdx.x * 256 + threadIdx.x;
    int row = idx >> 8;
    int c4  = idx & 255;
    const float* wp = (row < 64) ? Wk + (size_t)row * 1024
                    : (row < 128) ? Wq + (size_t)(row - 64) * 1024
                                  : Wv + (size_t)(row - 128) * 1024;
    float4 f = *reinterpret_cast<const float4*>(wp + c4 * 4);
    bf16x4 v; v[0] = (__bf16)f.x; v[1] = (__bf16)f.y; v[2] = (__bf16)f.z; v[3] = (__bf16)f.w;
    *reinterpret_cast<bf16x4*>(&wbf[(size_t)row * 1024 + c4 * 4]) = v;
}

// ---------------- Kernel 1: fused QKV projection GEMM, 32x48 wave tiles (r15 exact) ----------------
__global__ __launch_bounds__(512) void proj_kernel(
    const float* __restrict__ x, const __bf16* __restrict__ wbf,
    __bf16* __restrict__ kbuf, __bf16* __restrict__ qbuf, __bf16* __restrict__ vtbuf)
{
    __shared__ __align__(16) __bf16 Slds[2][256 * LDP];   // rows 0..63 A, 64..255 W
    __shared__ __align__(16) __bf16 Vtl[64 * LDP];

    const int tid  = threadIdx.x;
    const int lane = tid & 63;
    const int wid  = tid >> 6;     // 0..7
    const int wm   = wid >> 2;     // 0..1 : 32-row group
    const int wn   = wid & 3;      // 0..3 : 48-col group
    const int mbase = blockIdx.x * 64;

    const int cl = lane & 15;
    const int e0 = (lane >> 4) * 8;
    const int r0 = (lane >> 4) * 4;

    const int arow = tid >> 3, acg = tid & 7;
    const float* aptr = x + (size_t)(mbase + arow) * 1024 + acg * 8;

    float4 a0a, a0b, a1a, a1b;
    bf16x8 w0[3], w1[3];

#define ISSUE(aA, aB, wset, kb) { \
    aA = *reinterpret_cast<const float4*>(aptr + (kb)); \
    aB = *reinterpret_cast<const float4*>(aptr + (kb) + 4); \
    _Pragma("unroll") \
    for (int i_ = 0; i_ < 3; i_++) { \
        int c_ = i_ * 512 + tid; \
        wset[i_] = *reinterpret_cast<const bf16x8*>(&wbf[(size_t)(c_ >> 3) * 1024 + (kb) + (c_ & 7) * 8]); \
    } }

#define COMMIT(aA, aB, wset, bufi) { \
    bf16x8 av_; \
    av_[0] = (__bf16)aA.x; av_[1] = (__bf16)aA.y; av_[2] = (__bf16)aA.z; av_[3] = (__bf16)aA.w; \
    av_[4] = (__bf16)aB.x; av_[5] = (__bf16)aB.y; av_[6] = (__bf16)aB.z; av_[7] = (__bf16)aB.w; \
    *reinterpret_cast<bf16x8*>(&Slds[bufi][arow * LDP + acg * 8]) = av_; \
    _Pragma("unroll") \
    for (int i_ = 0; i_ < 3; i_++) { \
        int c_ = i_ * 512 + tid; \
        *reinterpret_cast<bf16x8*>(&Slds[bufi][(64 + (c_ >> 3)) * LDP + (c_ & 7) * 8]) = wset[i_]; \
    } }

    f32x4 acc[2][3];
    #pragma unroll
    for (int m2 = 0; m2 < 2; m2++)
        #pragma unroll
        for (int nf = 0; nf < 3; nf++) acc[m2][nf] = (f32x4){0.f, 0.f, 0.f, 0.f};

    ISSUE(a0a, a0b, w0, 0);
    COMMIT(a0a, a0b, w0, 0);
    ISSUE(a1a, a1b, w1, 64);
    BAR();

    #pragma unroll 2
    for (int j = 0; j < 16; j++) {
        if (j < 14) {
            if (j & 1) { ISSUE(a1a, a1b, w1, (j + 2) * 64); }
            else       { ISSUE(a0a, a0b, w0, (j + 2) * 64); }
        }
        const __bf16* buf = Slds[j & 1];
        #pragma unroll
        for (int kk = 0; kk < 2; kk++) {
            bf16x8 a[2], b[3];
            #pragma unroll
            for (int m2 = 0; m2 < 2; m2++)
                a[m2] = *reinterpret_cast<const bf16x8*>(&buf[(wm * 32 + m2 * 16 + cl) * LDP + kk * 32 + e0]);
            #pragma unroll
            for (int nf = 0; nf < 3; nf++)
                b[nf] = *reinterpret_cast<const bf16x8*>(&buf[(64 + wn * 48 + nf * 16 + cl) * LDP + kk * 32 + e0]);
            #pragma unroll
            for (int m2 = 0; m2 < 2; m2++)
                #pragma unroll
                for (int nf = 0; nf < 3; nf++)
                    acc[m2][nf] = __builtin_amdgcn_mfma_f32_16x16x32_bf16(a[m2], b[nf], acc[m2][nf], 0, 0, 0);
        }
        if (j < 15) {
            if (j & 1) { COMMIT(a0a, a0b, w0, 0); }
            else       { COMMIT(a1a, a1b, w1, 1); }
            BAR();
        }
    }
#undef ISSUE
#undef COMMIT

    #pragma unroll
    for (int m2 = 0; m2 < 2; m2++)
        #pragma unroll
        for (int nf = 0; nf < 3; nf++) {
            int c = wn * 48 + nf * 16 + cl;
            #pragma unroll
            for (int r = 0; r < 4; r++) {
                int mrel = wm * 32 + m2 * 16 + r0 + r;
                float v = acc[m2][nf][r];
                if (c < 64)        kbuf[(size_t)(mbase + mrel) * 64 + c]         = (__bf16)v;
                else if (c < 128)  qbuf[(size_t)(mbase + mrel) * 64 + (c - 64)]  = (__bf16)v;
                else               Vtl[(c - 128) * LDP + mrel]                   = (__bf16)v;
            }
        }
    __syncthreads();
    {
        int b   = mbase >> 11;
        int tof = mbase & 2047;
        int h   = tid >> 3;          // 0..63
        int seg = tid & 7;           // 8 bf16 each
        bf16x8 v8 = *reinterpret_cast<const bf16x8*>(&Vtl[h * LDP + seg * 8]);
        *reinterpret_cast<bf16x8*>(&vtbuf[(size_t)b * 64 * 2048 + (size_t)h * 2048 + tof + seg * 8]) = v8;
    }
}

// ---------------- Kernel 2: flash attention, 4 waves x 2 subtiles, 128 q-rows/block (r18 exact) ----
__global__ __launch_bounds__(256) void attn_kernel(
    const __bf16* __restrict__ qbuf, const __bf16* __restrict__ kbuf,
    const __bf16* __restrict__ vtbuf, const unsigned* __restrict__ maskw,
    float* __restrict__ out, __bf16* __restrict__ accpart, float* __restrict__ mlpart,
    int nsplit, int tps)
{
    __shared__ __align__(16) __bf16 Klds[64 * KLDP];        // [kv][h]
    __shared__ __align__(16) __bf16 Vlds[64 * VLDP];        // [h][kv]
    __shared__ __align__(16) __bf16 Plds[4][2][16 * PLDP];  // [wave][sub][q][kv]

    const int tid  = threadIdx.x;
    const int lane = tid & 63;
    const int w    = tid >> 6;          // 0..3
    const int wg   = blockIdx.x;
    const int b    = wg & 7;            // XCD-local batch
    const int rr_  = wg >> 3;
    const int qt   = rr_ & 15;          // 16 q-tiles of 128 rows
    const int sp   = rr_ >> 4;

    const int jbeg = sp * tps;
    const int jend = min((sp + 1) * tps, 2 * qt + 2);   // 64-wide kv tiles

    if (nsplit > 1 && jbeg >= jend) {
        for (int i = tid; i < 128; i += 256) {
            int qrow = qt * 128 + i;
            if ((maskw[b * 64 + (qrow >> 5)] >> (qrow & 31)) & 1u) {
                size_t mo = ((size_t)(b * nsplit + sp) * 2048 + qrow) * 2;
                mlpart[mo] = -INFINITY; mlpart[mo + 1] = 0.f;
            }
        }
        return;
    }

    const int cl = lane & 15;
    const int e0 = (lane >> 4) * 8;
    const int r0 = (lane >> 4) * 4;
    const int qs0 = qt * 128 + w * 16 + cl;   // subtile 0 q-row (lane-local)
    const int qs1 = qs0 + 64;                 // subtile 1 q-row

    bf16x8 aq0[2], aq1[2];
    #pragma unroll
    for (int kk = 0; kk < 2; kk++) {
        aq0[kk] = *reinterpret_cast<const bf16x8*>(&qbuf[((size_t)b * 2048 + qs0) * 64 + kk * 32 + e0]);
        aq1[kk] = *reinterpret_cast<const bf16x8*>(&qbuf[((size_t)b * 2048 + qs1) * 64 + kk * 32 + e0]);
    }

    float m0 = -INFINITY, l0 = 0.f, m1 = -INFINITY, l1 = 0.f;
    f32x4 acc0[4], acc1[4];
    #pragma unroll
    for (int hf = 0; hf < 4; hf++) { acc0[hf] = (f32x4){0.f,0.f,0.f,0.f}; acc1[hf] = (f32x4){0.f,0.f,0.f,0.f}; }

    const __bf16* kb  = kbuf  + (size_t)b * 2048 * 64;
    const __bf16* vtb = vtbuf + (size_t)b * 64 * 2048;

    // staging: 256 threads, thread -> row tid>>2 (0..63), 16-elem quarter (tid&3)
    const int srow = tid >> 2;
    const int sc   = (tid & 3) * 16;
    bf16x8 stk[2], stv[2];

#define KV_ISSUE(jj) { _Pragma("unroll") for (int i_ = 0; i_ < 2; i_++) { \
    stk[i_] = *reinterpret_cast<const bf16x8*>(&kb[(size_t)((jj) * 64 + srow) * 64 + sc + i_ * 8]); \
    stv[i_] = *reinterpret_cast<const bf16x8*>(&vtb[(size_t)srow * 2048 + (jj) * 64 + sc + i_ * 8]); } }

#define KV_COMMIT() { _Pragma("unroll") for (int i_ = 0; i_ < 2; i_++) { \
    *reinterpret_cast<bf16x8*>(&Klds[srow * KLDP + sc + i_ * 8]) = stk[i_]; \
    *reinterpret_cast<bf16x8*>(&Vlds[srow * VLDP + sc + i_ * 8]) = stv[i_]; } }

#define SOFTMAX(S, mS, lS, accS, qsS, su) { \
    float tmax = -INFINITY; \
    _Pragma("unroll") for (int jf = 0; jf < 4; jf++) { \
        unsigned mw = (jf < 2) ? mw0 : mw1; \
        _Pragma("unroll") for (int r = 0; r < 4; r++) { \
            int kvl = jf * 16 + r0 + r; \
            bool ok = ((mw >> (kvl & 31)) & 1u) && (j * 64 + kvl <= qsS); \
            float sv = S[jf][r] * 0.125f; \
            sv = ok ? sv : -INFINITY; \
            S[jf][r] = sv; tmax = fmaxf(tmax, sv); } } \
    tmax = fmaxf(tmax, __shfl_xor(tmax, 16)); \
    tmax = fmaxf(tmax, __shfl_xor(tmax, 32)); \
    if (!__all(tmax <= mS + 8.f)) { \
        float mn = fmaxf(mS, tmax); \
        float alpha = __expf(mS - mn); \
        lS *= alpha; mS = mn; \
        _Pragma("unroll") for (int hf = 0; hf < 4; hf++) \
            _Pragma("unroll") for (int r = 0; r < 4; r++) accS[hf][r] *= alpha; \
    } \
    float rs = 0.f; \
    _Pragma("unroll") for (int jf = 0; jf < 4; jf++) \
        _Pragma("unroll") for (int r = 0; r < 4; r++) { \
            float p = (mS == -INFINITY) ? 0.f : __expf(S[jf][r] - mS); \
            S[jf][r] = p; rs += p; } \
    rs += __shfl_xor(rs, 16); \
    rs += __shfl_xor(rs, 32); \
    lS += rs; \
    _Pragma("unroll") for (int jf = 0; jf < 4; jf++) { \
        bf16x4 p4; \
        _Pragma("unroll") for (int r = 0; r < 4; r++) p4[r] = (__bf16)S[jf][r]; \
        *reinterpret_cast<bf16x4*>(&Plds[w][su][cl * PLDP + jf * 16 + r0]) = p4; } }

    const int nt = jend - jbeg;
    KV_ISSUE(jbeg);
    KV_COMMIT();
    if (nt > 1) KV_ISSUE(jbeg + 1);
    BAR();

    for (int t = 0; t < nt; t++) {
        const int j = jbeg + t;

        f32x4 s0[4], s1[4];
        __builtin_amdgcn_s_setprio(1);
        #pragma unroll
        for (int jf = 0; jf < 4; jf++) {
            f32x4 t0 = (f32x4){0.f,0.f,0.f,0.f}, t1 = (f32x4){0.f,0.f,0.f,0.f};
            #pragma unroll
            for (int kk = 0; kk < 2; kk++) {
                bf16x8 bk = *reinterpret_cast<const bf16x8*>(&Klds[(jf * 16 + cl) * KLDP + kk * 32 + e0]);
                t0 = __builtin_amdgcn_mfma_f32_16x16x32_bf16(bk, aq0[kk], t0, 0, 0, 0);
                t1 = __builtin_amdgcn_mfma_f32_16x16x32_bf16(bk, aq1[kk], t1, 0, 0, 0);
            }
            s0[jf] = t0; s1[jf] = t1;
        }
        __builtin_amdgcn_s_setprio(0);

        const unsigned mw0 = maskw[b * 64 + j * 2];
        const unsigned mw1 = maskw[b * 64 + j * 2 + 1];
        SOFTMAX(s0, m0, l0, acc0, qs0, 0);
        SOFTMAX(s1, m1, l1, acc1, qs1, 1);

        __builtin_amdgcn_s_setprio(1);
        #pragma unroll
        for (int kk = 0; kk < 2; kk++) {
            bf16x8 p0 = *reinterpret_cast<const bf16x8*>(&Plds[w][0][cl * PLDP + kk * 32 + e0]);
            bf16x8 p1 = *reinterpret_cast<const bf16x8*>(&Plds[w][1][cl * PLDP + kk * 32 + e0]);
            #pragma unroll
            for (int hf = 0; hf < 4; hf++) {
                bf16x8 av = *reinterpret_cast<const bf16x8*>(&Vlds[(hf * 16 + cl) * VLDP + kk * 32 + e0]);
                acc0[hf] = __builtin_amdgcn_mfma_f32_16x16x32_bf16(av, p0, acc0[hf], 0, 0, 0);
                acc1[hf] = __builtin_amdgcn_mfma_f32_16x16x32_bf16(av, p1, acc1[hf], 0, 0, 0);
            }
        }
        __builtin_amdgcn_s_setprio(0);

        BAR();
        if (t + 1 < nt) {
            KV_COMMIT();
            if (t + 2 < nt) KV_ISSUE(j + 2);
            BAR();
        }
    }
#undef KV_ISSUE
#undef KV_COMMIT
#undef SOFTMAX

    const bool mq0 = (maskw[b * 64 + (qs0 >> 5)] >> (qs0 & 31)) & 1u;
    const bool mq1 = (maskw[b * 64 + (qs1 >> 5)] >> (qs1 & 31)) & 1u;
    if (nsplit == 1) {
        #pragma unroll
        for (int hf = 0; hf < 4; hf++)
            #pragma unroll
            for (int r = 0; r < 4; r++) {
                float v0 = (l0 > 0.f && mq0) ? acc0[hf][r] / l0 : 0.f;
                float v1 = (l1 > 0.f && mq1) ? acc1[hf][r] / l1 : 0.f;
                out[((size_t)b * 2048 + qs0) * 64 + hf * 16 + r0 + r] = v0;
                out[((size_t)b * 2048 + qs1) * 64 + hf * 16 + r0 + r] = v1;
            }
    } else {
        if (mq0) {
            #pragma unroll
            for (int hf = 0; hf < 4; hf++) {
                bf16x4 p4;
                #pragma unroll
                for (int r = 0; r < 4; r++) p4[r] = (__bf16)acc0[hf][r];
                *reinterpret_cast<bf16x4*>(&accpart[((size_t)(b * nsplit + sp) * 2048 + qs0) * 64 + hf * 16 + r0]) = p4;
            }
        }
        if (mq1) {
            #pragma unroll
            for (int hf = 0; hf < 4; hf++) {
                bf16x4 p4;
                #pragma unroll
                for (int r = 0; r < 4; r++) p4[r] = (__bf16)acc1[hf][r];
                *reinterpret_cast<bf16x4*>(&accpart[((size_t)(b * nsplit + sp) * 2048 + qs1) * 64 + hf * 16 + r0]) = p4;
            }
        }
        if (lane < 16) {
            if (mq0) {
                size_t mo0 = ((size_t)(b * nsplit + sp) * 2048 + qs0) * 2;
                mlpart[mo0] = m0; mlpart[mo0 + 1] = l0;
            }
            if (mq1) {
                size_t mo1 = ((size_t)(b * nsplit + sp) * 2048 + qs1) * 2;
                mlpart[mo1] = m1; mlpart[mo1 + 1] = l1;
            }
        }
    }
}

// ---------------- Kernel 3: combine bf16 partials, 4 h per thread ----------------
template<int NS>
__global__ __launch_bounds__(256) void combine_kernel(
    const __bf16* __restrict__ accpart, const float* __restrict__ mlpart,
    const unsigned* __restrict__ maskw, float* __restrict__ out)
{
    int idx = blockIdx.x * 256 + threadIdx.x;   // 0 .. 16384*16-1
    int qglob = idx >> 4;                        // b*2048 + qrow
    int h4 = (idx & 15) * 4;
    int b = qglob >> 11;
    int qrow = qglob & 2047;

    float4 o = {0.f, 0.f, 0.f, 0.f};
    if (!((maskw[b * 64 + (qrow >> 5)] >> (qrow & 31)) & 1u)) {
        *reinterpret_cast<float4*>(&out[(size_t)qglob * 64 + h4]) = o;
        return;
    }

    float m_s[NS], l_s[NS];
    float M = -INFINITY;
    #pragma unroll
    for (int s = 0; s < NS; s++) {
        size_t mo = ((size_t)(b * NS + s) * 2048 + qrow) * 2;
        m_s[s] = mlpart[mo];
        l_s[s] = mlpart[mo + 1];
        M = fmaxf(M, m_s[s]);
    }
    if (M == -INFINITY) {
        *reinterpret_cast<float4*>(&out[(size_t)qglob * 64 + h4]) = o;
        return;
    }

    float L = 0.f;
    float O0 = 0.f, O1 = 0.f, O2 = 0.f, O3 = 0.f;
    #pragma unroll
    for (int s = 0; s < NS; s++) {
        if (m_s[s] > -INFINITY) {
            float wgt = __expf(m_s[s] - M);
            L += l_s[s] * wgt;
            bf16x4 a = *reinterpret_cast<const bf16x4*>(
                &accpart[((size_t)(b * NS + s) * 2048 + qrow) * 64 + h4]);
            O0 += wgt * (float)a[0];
            O1 += wgt * (float)a[1];
            O2 += wgt * (float)a[2];
            O3 += wgt * (float)a[3];
        }
    }
    if (L > 0.f) { o.x = O0 / L; o.y = O1 / L; o.z = O2 / L; o.w = O3 / L; }
    *reinterpret_cast<float4*>(&out[(size_t)qglob * 64 + h4]) = o;
}

extern "C" void kernel_launch(void* const* d_in, const int* in_sizes, int n_in,
                              void* d_out, int out_size, void* d_ws, size_t ws_size,
                              hipStream_t stream) {
    const float* x  = (const float*)d_in[0];
    const float* Wk = (const float*)d_in[1];
    const float* Wq = (const float*)d_in[2];
    const float* Wv = (const float*)d_in[3];
    const int* mask = (const int*)d_in[4];
    float* out = (float*)d_out;

    const size_t NTOK = 8 * 2048;
    __bf16* kbuf  = (__bf16*)d_ws;                    // [16384][64]
    __bf16* qbuf  = kbuf + NTOK * 64;                 // [16384][64]
    __bf16* vtbuf = qbuf + NTOK * 64;                 // [8][64][2048]
    __bf16* wbf   = vtbuf + (size_t)8 * 64 * 2048;    // [192][1024]
    unsigned* maskw = (unsigned*)(wbf + (size_t)192 * 1024);   // [512]
    const size_t base_bytes = NTOK * 64 * 2 * 2 + (size_t)8 * 64 * 2048 * 2
                            + (size_t)192 * 1024 * 2 + 512 * 4;

    const size_t acc_per_split = NTOK * 64 * 2;       // bf16: 2 MiB
    const size_t ml_per_split  = NTOK * 2 * 4;        // 128 KiB
    int nsplit = 1;
    if (ws_size >= base_bytes + 4 * (acc_per_split + ml_per_split))      nsplit = 4;
    else if (ws_size >= base_bytes + 2 * (acc_per_split + ml_per_split)) nsplit = 2;

    __bf16* accpart = (__bf16*)((char*)d_ws + base_bytes);
    float*  mlpart  = (float*)(accpart + NTOK * 64 * nsplit);

    wconv_kernel<<<193, 256, 0, stream>>>(Wk, Wq, Wv, mask, wbf, maskw);
    proj_kernel<<<256, 512, 0, stream>>>(x, wbf, kbuf, qbuf, vtbuf);
    attn_kernel<<<8 * 16 * nsplit, 256, 0, stream>>>(
        qbuf, kbuf, vtbuf, maskw, out, accpart, mlpart, nsplit, 32 / nsplit);
    if (nsplit == 4)
        combine_kernel<4><<<(16384 * 16) / 256, 256, 0, stream>>>(accpart, mlpart, maskw, out);
    else if (nsplit == 2)
        combine_kernel<2><<<(16384 * 16) / 256, 256, 0, stream>>>(accpart, mlpart, maskw, out);
}